// Round 2
// baseline (373.180 us; speedup 1.0000x reference)
//
#include <hip/hip_runtime.h>
#include <hip/hip_bf16.h>

// AggregationMPNN: B=64, N=64, E=16, H=M=OUT=128, 3 passes.
// Design: one block per graph (64 blocks x 512 threads = 8 waves).
// All state (hidden hi/lo bf16, HA/HM projections, messages, nbr lists) in LDS.
// GEMMs via mfma_f32_16x16x32_bf16 with hi/lo split (3-product) for f32-class accuracy.
// Weights pre-packed into fragment-linear bf16 hi/lo by a prep kernel.

typedef __attribute__((ext_vector_type(8))) short short8;
typedef __attribute__((ext_vector_type(4))) float f32x4;

#define PK_TOTAL (352 * 512)   // ushort elems per plane (hi / lo)

__device__ __forceinline__ unsigned short f2bf(float x) {
    unsigned u = __float_as_uint(x);
    u += 0x7FFF + ((u >> 16) & 1);          // round-to-nearest-even
    return (unsigned short)(u >> 16);
}
__device__ __forceinline__ float bf2f(unsigned short h) {
    return __uint_as_float((unsigned)h << 16);
}
__device__ __forceinline__ float sigmoidf_(float x) { return 1.f / (1.f + __expf(-x)); }

__device__ __forceinline__ f32x4 mfma16(short8 a, short8 b, f32x4 c) {
    return __builtin_amdgcn_mfma_f32_16x16x32_bf16(a, b, c, 0, 0, 0);
}

// ---------------------------------------------------------------------------
// Prep: pack 6 weight matrices into MFMA B-fragment-linear bf16 hi/lo planes.
// Tile (kb,nt) frag: lane l holds B[k=kb*32+(l>>4)*8+j][n=nt*16+(l&15)], j=0..7.
// Packed at pk[tile*512 + l*8 + j]; lo plane at +PK_TOTAL.
// Tile bases: Wam[0,64) KB=4 | Wihrz[64,192) KB=8 | Win[192,224) KB=4 |
//             Whn[224,256) KB=4 | Wgate[256,320) KB=8 | Wemb[320,352) KB=4
// ---------------------------------------------------------------------------
__global__ __launch_bounds__(64) void prep_pack(
    const float* __restrict__ Wa, const float* __restrict__ Wm,
    const float* __restrict__ Wi, const float* __restrict__ Wh,
    const float* __restrict__ Wg, const float* __restrict__ We,
    unsigned short* __restrict__ pk)
{
    int t = blockIdx.x, l = threadIdx.x;
    short8 hv8, lv8;
#pragma unroll
    for (int j = 0; j < 8; j++) {
        int kb, nt;
        float x;
        int kbase = (l >> 4) * 8 + j;
        int nbase = l & 15;
        if (t < 64)       { int lt = t;       kb = lt & 3; nt = lt >> 2;
            int k = kb*32 + kbase, n = nt*16 + nbase;
            x = (n < 128) ? Wa[k*128 + n] : Wm[k*128 + n - 128]; }
        else if (t < 192) { int lt = t - 64;  kb = lt & 7; nt = lt >> 3;
            int k = kb*32 + kbase, n = nt*16 + nbase;
            x = (k < 128) ? Wi[k*384 + n] : Wh[(k-128)*384 + n]; }
        else if (t < 224) { int lt = t - 192; kb = lt & 3; nt = lt >> 2;
            int k = kb*32 + kbase, n = nt*16 + nbase;
            x = Wi[k*384 + 256 + n]; }
        else if (t < 256) { int lt = t - 224; kb = lt & 3; nt = lt >> 2;
            int k = kb*32 + kbase, n = nt*16 + nbase;
            x = Wh[k*384 + 256 + n]; }
        else if (t < 320) { int lt = t - 256; kb = lt & 7; nt = lt >> 3;
            int k = kb*32 + kbase, n = nt*16 + nbase;
            x = Wg[k*128 + n]; }
        else              { int lt = t - 320; kb = lt & 3; nt = lt >> 2;
            int k = kb*32 + kbase, n = nt*16 + nbase;
            x = We[k*128 + n]; }
        unsigned short h = f2bf(x);
        hv8[j] = (short)h;
        lv8[j] = (short)f2bf(x - bf2f(h));
    }
    size_t off = (size_t)t * 512 + l * 8;
    *(short8*)&pk[off] = hv8;
    *(short8*)&pk[PK_TOTAL + off] = lv8;
}

// ---------------------------------------------------------------------------
// Main fused kernel: one block per graph.
// ---------------------------------------------------------------------------
__global__ __launch_bounds__(512) void mpnn_main(
    const float* __restrict__ nodes, const float* __restrict__ edges,
    const float* __restrict__ W_att, const float* __restrict__ W_msg,
    const float* __restrict__ b_msg, const float* __restrict__ b_i,
    const float* __restrict__ b_h, const float* __restrict__ b_gate,
    const float* __restrict__ b_emb,
    const unsigned short* __restrict__ pk, float* __restrict__ out)
{
    // bf16 hi/lo arrays are XOR-swizzled: element (row,c) at byte (c*2)^((row&7)<<4) within row.
    __shared__ unsigned short h_hi[64*128], h_lo[64*128];     // 32 KB
    __shared__ unsigned short mg_hi[64*128], mg_lo[64*128];   // 32 KB
    __shared__ float HAHM[64*256];                            // 64 KB (reused as `red` at readout)
    __shared__ unsigned short nbr_s[64*64];                   // 8 KB
    __shared__ float WaE[16*128], WmE[16*128];                // 16 KB
    __shared__ int deg_s[64];

    const int tid = threadIdx.x;
    const int w = tid >> 6, l = tid & 63;
    const int b = blockIdx.x;
    const int mt = w >> 1, half = w & 1;
    const int arow = mt*16 + (l & 15);            // A-fragment row for this lane
    const int rowb = mt*16 + (l >> 4) * 4;        // D-fragment row base for this lane

    // ---- init hidden = nodes (split bf16), load edge-type weight rows ----
    for (int idx = tid; idx < 8192; idx += 512) {
        int row = idx >> 7, col = idx & 127;
        float v = nodes[(size_t)b*8192 + idx];
        unsigned short hh = f2bf(v);
        int byt = (col*2) ^ ((row & 7) << 4);
        *(unsigned short*)((char*)h_hi + row*256 + byt) = hh;
        *(unsigned short*)((char*)h_lo + row*256 + byt) = f2bf(v - bf2f(hh));
    }
    for (int idx = tid; idx < 2048; idx += 512) {
        WaE[idx] = W_att[128*128 + idx];
        WmE[idx] = W_msg[128*128 + idx];
    }
    // ---- adjacency: wave w handles rows i = w*8..w*8+7; lane j scans one-hot ----
    for (int ii = 0; ii < 8; ii++) {
        int i = w*8 + ii;
        const float4* ep = (const float4*)&edges[(size_t)((b*64 + i)*64 + l) * 16];
        int et = -1;
#pragma unroll
        for (int q = 0; q < 4; q++) {
            float4 v = ep[q];
            if (v.x > 0.5f) et = q*4 + 0;
            if (v.y > 0.5f) et = q*4 + 1;
            if (v.z > 0.5f) et = q*4 + 2;
            if (v.w > 0.5f) et = q*4 + 3;
        }
        unsigned long long mask = __ballot(et >= 0);
        int pos = __popcll(mask & ((1ull << l) - 1ull));
        if (et >= 0) nbr_s[i*64 + pos] = (unsigned short)(l | (et << 8));
        if (l == 0) deg_s[i] = (int)__popcll(mask);
    }
    __syncthreads();

    for (int pass = 0; pass < 3; pass++) {
        // ===== P-GEMM: HAHM[64x256] = h @ [Wa|Wm]  (K=128) =====
        {
            short8 ah[4], al[4];
#pragma unroll
            for (int kb = 0; kb < 4; kb++) {
                int byt = (kb*64 + ((l >> 4) * 16)) ^ ((arow & 7) << 4);
                ah[kb] = *(const short8*)((const char*)h_hi + arow*256 + byt);
                al[kb] = *(const short8*)((const char*)h_lo + arow*256 + byt);
            }
#pragma unroll
            for (int nt2 = 0; nt2 < 8; nt2++) {
                int nt = half*8 + nt2;
                f32x4 acc = {0.f, 0.f, 0.f, 0.f};
#pragma unroll
                for (int kb = 0; kb < 4; kb++) {
                    const unsigned short* p = pk + (size_t)(nt*4 + kb)*512 + l*8;
                    short8 bh = *(const short8*)p;
                    short8 bl = *(const short8*)(p + PK_TOTAL);
                    acc = mfma16(ah[kb], bh, acc);
                    acc = mfma16(ah[kb], bl, acc);
                    acc = mfma16(al[kb], bh, acc);
                }
                int col = nt*16 + (l & 15);
#pragma unroll
                for (int r = 0; r < 4; r++)
                    HAHM[(rowb + r)*256 + col] = acc[r];
            }
        }
        __syncthreads();

        // ===== per-node attention messages (online softmax, 2 channels/lane) =====
        {
            float bm0 = b_msg[2*l], bm1 = b_msg[2*l + 1];
            for (int ii = 0; ii < 8; ii++) {
                int i = w*8 + ii;
                int d = deg_s[i];
                float m0 = -3e38f, m1 = -3e38f, sw0 = 0.f, sw1 = 0.f, a0 = 0.f, a1 = 0.f;
                for (int k = 0; k < d; k++) {
                    int pkt = nbr_s[i*64 + k];           // wave-uniform broadcast
                    int j = pkt & 63, e = pkt >> 8;
                    float2 ha = *(const float2*)&HAHM[j*256 + 2*l];
                    float2 hm = *(const float2*)&HAHM[j*256 + 128 + 2*l];
                    float2 wa = *(const float2*)&WaE[e*128 + 2*l];
                    float2 wm = *(const float2*)&WmE[e*128 + 2*l];
                    float e0 = ha.x + wa.x, e1 = ha.y + wa.y;
                    float q0 = hm.x + wm.x, q1 = hm.y + wm.y;
                    float n0 = fmaxf(m0, e0), n1 = fmaxf(m1, e1);
                    float s0 = __expf(m0 - n0), s1 = __expf(m1 - n1);
                    float w0 = __expf(e0 - n0), w1 = __expf(e1 - n1);
                    sw0 = sw0*s0 + w0;       sw1 = sw1*s1 + w1;
                    a0  = a0*s0 + w0*q0;     a1  = a1*s1 + w1*q1;
                    m0 = n0; m1 = n1;
                }
                float r0 = d ? (a0/sw0 + bm0) : 0.f;
                float r1 = d ? (a1/sw1 + bm1) : 0.f;
                unsigned short h0 = f2bf(r0), h1 = f2bf(r1);
                unsigned short g0 = f2bf(r0 - bf2f(h0)), g1 = f2bf(r1 - bf2f(h1));
                int byt = (4*l) ^ ((i & 7) << 4);
                *(unsigned*)((char*)mg_hi + i*256 + byt) = (unsigned)h0 | ((unsigned)h1 << 16);
                *(unsigned*)((char*)mg_lo + i*256 + byt) = (unsigned)g0 | ((unsigned)g1 << 16);
            }
        }
        __syncthreads();

        // ===== GRU: acc = [msg|h] @ [Wi;Wh] for r,z; msg@Wi_n; h@Wh_n; elementwise =====
        {
            short8 mh[4], ml[4], hh[4], hl[4];
#pragma unroll
            for (int kb = 0; kb < 4; kb++) {
                int byt = (kb*64 + ((l >> 4) * 16)) ^ ((arow & 7) << 4);
                mh[kb] = *(const short8*)((const char*)mg_hi + arow*256 + byt);
                ml[kb] = *(const short8*)((const char*)mg_lo + arow*256 + byt);
                hh[kb] = *(const short8*)((const char*)h_hi + arow*256 + byt);
                hl[kb] = *(const short8*)((const char*)h_lo + arow*256 + byt);
            }
            float hold[4][4];
            int dmask[4];
#pragma unroll
            for (int r = 0; r < 4; r++) dmask[r] = deg_s[rowb + r] > 0;
#pragma unroll
            for (int nt2 = 0; nt2 < 4; nt2++) {
                int col = (half*4 + nt2)*16 + (l & 15);
#pragma unroll
                for (int r = 0; r < 4; r++) {
                    int row = rowb + r;
                    int byt = (col*2) ^ ((row & 7) << 4);
                    hold[nt2][r] = bf2f(*(const unsigned short*)((const char*)h_hi + row*256 + byt))
                                 + bf2f(*(const unsigned short*)((const char*)h_lo + row*256 + byt));
                }
            }
            __syncthreads();   // all LDS reads of h/mg complete before h is overwritten

#pragma unroll
            for (int nt2 = 0; nt2 < 4; nt2++) {
                int nt = half*4 + nt2;
                int col = nt*16 + (l & 15);
                f32x4 ar = {0,0,0,0}, az = {0,0,0,0}, ain = {0,0,0,0}, ahn = {0,0,0,0};
#pragma unroll
                for (int kb = 0; kb < 8; kb++) {
                    short8 Ah = (kb < 4) ? mh[kb] : hh[kb-4];
                    short8 Al = (kb < 4) ? ml[kb] : hl[kb-4];
                    {   const unsigned short* p = pk + (size_t)(64 + nt*8 + kb)*512 + l*8;
                        short8 bh2 = *(const short8*)p, bl2 = *(const short8*)(p + PK_TOTAL);
                        ar = mfma16(Ah, bh2, ar); ar = mfma16(Ah, bl2, ar); ar = mfma16(Al, bh2, ar); }
                    {   const unsigned short* p = pk + (size_t)(64 + (nt+8)*8 + kb)*512 + l*8;
                        short8 bh2 = *(const short8*)p, bl2 = *(const short8*)(p + PK_TOTAL);
                        az = mfma16(Ah, bh2, az); az = mfma16(Ah, bl2, az); az = mfma16(Al, bh2, az); }
                }
#pragma unroll
                for (int kb = 0; kb < 4; kb++) {
                    {   const unsigned short* p = pk + (size_t)(192 + nt*4 + kb)*512 + l*8;
                        short8 bh2 = *(const short8*)p, bl2 = *(const short8*)(p + PK_TOTAL);
                        ain = mfma16(mh[kb], bh2, ain); ain = mfma16(mh[kb], bl2, ain); ain = mfma16(ml[kb], bh2, ain); }
                    {   const unsigned short* p = pk + (size_t)(224 + nt*4 + kb)*512 + l*8;
                        short8 bh2 = *(const short8*)p, bl2 = *(const short8*)(p + PK_TOTAL);
                        ahn = mfma16(hh[kb], bh2, ahn); ahn = mfma16(hh[kb], bl2, ahn); ahn = mfma16(hl[kb], bh2, ahn); }
                }
                float brz_r = b_i[col] + b_h[col];
                float brz_z = b_i[128 + col] + b_h[128 + col];
                float b_in = b_i[256 + col], b_hn = b_h[256 + col];
#pragma unroll
                for (int r = 0; r < 4; r++) {
                    float rg = sigmoidf_(ar[r] + brz_r);
                    float zg = sigmoidf_(az[r] + brz_z);
                    float ng = tanhf(ain[r] + b_in + rg * (ahn[r] + b_hn));
                    float hn = (1.f - zg) * ng + zg * hold[nt2][r];
                    if (dmask[r]) {
                        int row = rowb + r;
                        int byt = (col*2) ^ ((row & 7) << 4);
                        unsigned short h16 = f2bf(hn);
                        *(unsigned short*)((char*)h_hi + row*256 + byt) = h16;
                        *(unsigned short*)((char*)h_lo + row*256 + byt) = f2bf(hn - bf2f(h16));
                    }
                }
            }
        }
        __syncthreads();
    }

    // ===== readout: out[b] = sum_i sigmoid([h|x]@Wg + bg) * (h@We + be) * mask =====
    {
        short8 hh[4], hl[4], xh, xl;
        short8 xhv[4], xlv[4];
#pragma unroll
        for (int kb = 0; kb < 4; kb++) {
            int byt = (kb*64 + ((l >> 4) * 16)) ^ ((arow & 7) << 4);
            hh[kb] = *(const short8*)((const char*)h_hi + arow*256 + byt);
            hl[kb] = *(const short8*)((const char*)h_lo + arow*256 + byt);
            const float* p = nodes + (size_t)b*8192 + arow*128 + kb*32 + (l >> 4) * 8;
#pragma unroll
            for (int j = 0; j < 8; j++) {
                float v = p[j];
                unsigned short hv = f2bf(v);
                xh[j] = (short)hv;
                xl[j] = (short)f2bf(v - bf2f(hv));
            }
            xhv[kb] = xh; xlv[kb] = xl;
        }
        int dmask[4];
#pragma unroll
        for (int r = 0; r < 4; r++) dmask[r] = deg_s[rowb + r] > 0;
        float* red = HAHM;   // HAHM is free now; reuse first 512 floats
#pragma unroll
        for (int nt2 = 0; nt2 < 4; nt2++) {
            int nt = half*4 + nt2;
            int col = nt*16 + (l & 15);
            f32x4 ae = {0,0,0,0}, ag = {0,0,0,0};
#pragma unroll
            for (int kb = 0; kb < 4; kb++) {
                const unsigned short* p = pk + (size_t)(320 + nt*4 + kb)*512 + l*8;
                short8 bh2 = *(const short8*)p, bl2 = *(const short8*)(p + PK_TOTAL);
                ae = mfma16(hh[kb], bh2, ae); ae = mfma16(hh[kb], bl2, ae); ae = mfma16(hl[kb], bh2, ae);
            }
#pragma unroll
            for (int kb = 0; kb < 8; kb++) {
                short8 Ah = (kb < 4) ? hh[kb] : xhv[kb-4];
                short8 Al = (kb < 4) ? hl[kb] : xlv[kb-4];
                const unsigned short* p = pk + (size_t)(256 + nt*8 + kb)*512 + l*8;
                short8 bh2 = *(const short8*)p, bl2 = *(const short8*)(p + PK_TOTAL);
                ag = mfma16(Ah, bh2, ag); ag = mfma16(Ah, bl2, ag); ag = mfma16(Al, bh2, ag);
            }
            float be = b_emb[col], bg = b_gate[col];
            float s = 0.f;
#pragma unroll
            for (int r = 0; r < 4; r++)
                if (dmask[r]) s += sigmoidf_(ag[r] + bg) * (ae[r] + be);
            s += __shfl_xor(s, 16);
            s += __shfl_xor(s, 32);
            if (l < 16) red[mt*128 + col] = s;
        }
        __syncthreads();
        if (tid < 128)
            out[(size_t)b*128 + tid] = red[tid] + red[128 + tid] + red[256 + tid] + red[384 + tid];
    }
}

// ---------------------------------------------------------------------------

extern "C" void kernel_launch(void* const* d_in, const int* in_sizes, int n_in,
                              void* d_out, int out_size, void* d_ws, size_t ws_size,
                              hipStream_t stream) {
    const float* nodes  = (const float*)d_in[0];
    const float* edges  = (const float*)d_in[1];
    const float* W_att  = (const float*)d_in[2];
    const float* W_msg  = (const float*)d_in[4];
    const float* b_msg  = (const float*)d_in[5];
    const float* W_i    = (const float*)d_in[6];
    const float* b_i    = (const float*)d_in[7];
    const float* W_h    = (const float*)d_in[8];
    const float* b_h    = (const float*)d_in[9];
    const float* W_gate = (const float*)d_in[10];
    const float* b_gate = (const float*)d_in[11];
    const float* W_emb  = (const float*)d_in[12];
    const float* b_emb  = (const float*)d_in[13];
    float* out = (float*)d_out;

    unsigned short* pkbuf = (unsigned short*)d_ws;   // 2 * 352*512 ushorts = 704 KB

    prep_pack<<<352, 64, 0, stream>>>(W_att, W_msg, W_i, W_h, W_gate, W_emb, pkbuf);
    mpnn_main<<<64, 512, 0, stream>>>(nodes, edges, W_att, W_msg, b_msg, b_i, b_h,
                                      b_gate, b_emb, pkbuf, out);
}

// Round 3
// 128.123 us; speedup vs baseline: 2.9127x; 2.9127x over previous
//
#include <hip/hip_runtime.h>
#include <hip/hip_bf16.h>

// AggregationMPNN: B=64, N=64, E=16, H=M=OUT=128, 3 passes.
// One block per graph (64 blocks x 512 thr). All GEMM B-operands staged to LDS.
// A-operands (h, msg, x) kept as bf16 hi/lo split (2-product MFMA); B single bf16.

typedef __attribute__((ext_vector_type(8))) short short8;
typedef __attribute__((ext_vector_type(4))) float f32x4;

// pk tile map (1 tile = 1 KB = 64 lanes x 16B fragment):
//   [0,64)    Wam   [nt16][kb4]          (h @ [Wa|Wm], K=128, N=256)
//   [64,256)  GRU   [grp4][gate3][ct2][kb8]  ([mg|h] @ [Wi;Wh], K=256, per-grp N=32)
//   [256,288) We    [nt8][kb4]
//   [288,320) Wg1   [nt8][kb4]           (h-part of W_gate)
//   [320,352) Wg2   [nt8][kb4]           (x-part of W_gate)
#define PK_TILES 352

// LDS byte offsets (total 147712 <= 163840)
#define OFF_HHI 0          // ushort[64*128] swizzled
#define OFF_HLO 16384
#define OFF_HA  32768      // ushort[64*128] row-linear (energies, bf16)
#define OFF_HM  49152      // float [64*128] row-linear
#define OFF_MGH 32768      // overlay: msg hi (swizzled, like h)
#define OFF_MGL 49152      // overlay: msg lo
#define OFF_RED 32768      // overlay: readout partials float[512]
#define OFF_B   81920      // 65536-byte staging buffer
#define OFF_WAE 81920      // overlay in Bbuf: float[2048]
#define OFF_WME 90112      // overlay in Bbuf: float[2048]
#define OFF_NBR 98304      // overlay in Bbuf: ushort[4096]
#define OFF_DEG 147456     // int[64]
#define LDS_BYTES 147712

__device__ __forceinline__ unsigned short f2bf(float x) {
    unsigned u = __float_as_uint(x);
    u += 0x7FFF + ((u >> 16) & 1);
    return (unsigned short)(u >> 16);
}
__device__ __forceinline__ float bf2f(unsigned short h) {
    return __uint_as_float((unsigned)h << 16);
}
__device__ __forceinline__ float sigmoidf_(float x) { return 1.f / (1.f + __expf(-x)); }
__device__ __forceinline__ f32x4 mfma16(short8 a, short8 b, f32x4 c) {
    return __builtin_amdgcn_mfma_f32_16x16x32_bf16(a, b, c, 0, 0, 0);
}

// ---------------------------------------------------------------------------
// Prep: pack weights (single bf16 plane) into fragment-linear tiles.
// Fragment: lane l, j=0..7 holds W[k = kb*32 + (l>>4)*8 + j][n-col], pk[t*512+l*8+j].
// ---------------------------------------------------------------------------
__global__ __launch_bounds__(64) void prep_pack(
    const float* __restrict__ Wa, const float* __restrict__ Wm,
    const float* __restrict__ Wi, const float* __restrict__ Wh,
    const float* __restrict__ Wg, const float* __restrict__ We,
    unsigned short* __restrict__ pk)
{
    int t = blockIdx.x, l = threadIdx.x;
    short8 v8;
#pragma unroll
    for (int j = 0; j < 8; j++) {
        int kk = (l >> 4) * 8 + j;
        int nb = l & 15;
        float x;
        if (t < 64) {                       // Wam
            int nt = t >> 2, kb = t & 3;
            int k = kb * 32 + kk, n = nt * 16 + nb;
            x = (n < 128) ? Wa[k * 128 + n] : Wm[k * 128 + n - 128];
        } else if (t < 256) {               // GRU
            int u = t - 64;
            int g = u / 48, r1 = u % 48;
            int gate = r1 >> 4, ct = (r1 >> 3) & 1, kb = r1 & 7;
            int k = kb * 32 + kk;
            int col = gate * 128 + g * 32 + ct * 16 + nb;
            x = (k < 128) ? Wi[k * 384 + col] : Wh[(k - 128) * 384 + col];
        } else if (t < 288) {               // We
            int u = t - 256; int nt = u >> 2, kb = u & 3;
            x = We[(kb * 32 + kk) * 128 + nt * 16 + nb];
        } else if (t < 320) {               // Wg1 (h rows)
            int u = t - 288; int nt = u >> 2, kb = u & 3;
            x = Wg[(kb * 32 + kk) * 128 + nt * 16 + nb];
        } else {                            // Wg2 (x rows)
            int u = t - 320; int nt = u >> 2, kb = u & 3;
            x = Wg[(128 + kb * 32 + kk) * 128 + nt * 16 + nb];
        }
        v8[j] = (short)f2bf(x);
    }
    *(short8*)&pk[(size_t)t * 512 + l * 8] = v8;
}

// ---------------------------------------------------------------------------
// Adjacency build (once): nbr_g[n*64+pos] = j | (etype<<8); deg_g[n].
// ---------------------------------------------------------------------------
__global__ __launch_bounds__(512) void build_adj(
    const float* __restrict__ edges, unsigned short* __restrict__ nbr_g,
    int* __restrict__ deg_g)
{
    int b = blockIdx.x;
    int w = threadIdx.x >> 6, l = threadIdx.x & 63;
    for (int ii = 0; ii < 8; ii++) {
        int i = w * 8 + ii;
        int n = b * 64 + i;
        const float4* ep = (const float4*)&edges[(size_t)(n * 64 + l) * 16];
        int et = -1;
#pragma unroll
        for (int q = 0; q < 4; q++) {
            float4 v = ep[q];
            if (v.x > 0.5f) et = q * 4 + 0;
            if (v.y > 0.5f) et = q * 4 + 1;
            if (v.z > 0.5f) et = q * 4 + 2;
            if (v.w > 0.5f) et = q * 4 + 3;
        }
        unsigned long long mask = __ballot(et >= 0);
        int pos = __popcll(mask & ((1ull << l) - 1ull));
        if (et >= 0) nbr_g[(size_t)n * 64 + pos] = (unsigned short)(l | (et << 8));
        if (l == 0) deg_g[n] = (int)__popcll(mask);
    }
}

// ---------------------------------------------------------------------------
// Main fused kernel: one block per graph, 8 waves.
// ---------------------------------------------------------------------------
__global__ __launch_bounds__(512, 2) void mpnn_main(
    const float* __restrict__ nodes, const float* __restrict__ W_att,
    const float* __restrict__ W_msg, const float* __restrict__ b_msg,
    const float* __restrict__ b_i, const float* __restrict__ b_h,
    const float* __restrict__ b_gate, const float* __restrict__ b_emb,
    const unsigned short* __restrict__ pk, const unsigned short* __restrict__ nbr_g,
    const int* __restrict__ deg_g, float* __restrict__ out)
{
    __shared__ __align__(16) char lds[LDS_BYTES];
    const int tid = threadIdx.x;
    const int w = tid >> 6, l = tid & 63;
    const int b = blockIdx.x;
    const int rowt = w & 3, colh8 = w >> 2;        // wave row-tile, col-half
    const int arow = rowt * 16 + (l & 15);          // A-fragment row
    const int rowb = rowt * 16 + (l >> 4) * 4;      // D-fragment row base
    int* degp = (int*)(lds + OFF_DEG);

    // ---- init: h = nodes (hi/lo bf16, swizzled), deg ----
    for (int idx = tid; idx < 8192; idx += 512) {
        int row = idx >> 7, col = idx & 127;
        float v = nodes[(size_t)b * 8192 + idx];
        unsigned short hh = f2bf(v);
        int byt = (col * 2) ^ ((row & 7) << 4);
        *(unsigned short*)(lds + OFF_HHI + row * 256 + byt) = hh;
        *(unsigned short*)(lds + OFF_HLO + row * 256 + byt) = f2bf(v - bf2f(hh));
    }
    if (tid < 64) degp[tid] = deg_g[b * 64 + tid];
    const float bm0 = b_msg[2 * l], bm1 = b_msg[2 * l + 1];
    __syncthreads();

    for (int pass = 0; pass < 3; pass++) {
        // ===== stage Wam (64 KB) =====
        for (int r2 = 0; r2 < 8; r2++) {
            int idx = r2 * 4096 + tid * 8;
            short8 v = *(const short8*)&pk[idx];
            *(short8*)(lds + OFF_B + idx * 2) = v;
        }
        __syncthreads();

        // ===== P-GEMM: [HA|HM] = h @ Wam =====
        {
            short8 ah[4], al[4];
#pragma unroll
            for (int kb = 0; kb < 4; kb++) {
                int byt = arow * 256 + ((kb * 64 + ((l >> 4) * 16)) ^ ((arow & 7) << 4));
                ah[kb] = *(const short8*)(lds + OFF_HHI + byt);
                al[kb] = *(const short8*)(lds + OFF_HLO + byt);
            }
#pragma unroll
            for (int nt2 = 0; nt2 < 8; nt2++) {
                int nt = colh8 * 8 + nt2;
                f32x4 acc = {0.f, 0.f, 0.f, 0.f};
#pragma unroll
                for (int kb = 0; kb < 4; kb++) {
                    short8 bf = *(const short8*)(lds + OFF_B + (nt * 4 + kb) * 1024 + l * 16);
                    acc = mfma16(ah[kb], bf, acc);
                    acc = mfma16(al[kb], bf, acc);
                }
                int col = nt * 16 + (l & 15);
                if (nt < 8) {
#pragma unroll
                    for (int r = 0; r < 4; r++)
                        *(unsigned short*)(lds + OFF_HA + (rowb + r) * 256 + col * 2) = f2bf(acc[r]);
                } else {
#pragma unroll
                    for (int r = 0; r < 4; r++)
                        *(float*)(lds + OFF_HM + (rowb + r) * 512 + (col - 128) * 4) = acc[r];
                }
            }
        }
        __syncthreads();

        // ===== load WaE/WmE (edge-type rows, f32) + nbr into Bbuf overlay =====
        {
            *(float4*)(lds + OFF_WAE + tid * 16) = *(const float4*)&W_att[16384 + tid * 4];
            *(float4*)(lds + OFF_WME + tid * 16) = *(const float4*)&W_msg[16384 + tid * 4];
            *(short8*)(lds + OFF_NBR + tid * 16) = *(const short8*)&nbr_g[(size_t)b * 4096 + tid * 8];
        }
        __syncthreads();

        // ===== attention messages (unnormalized exp; 2 ch/lane, 8 rows/wave) =====
        float resv[16];
        {
            const unsigned short* nbrp = (const unsigned short*)(lds + OFF_NBR);
#pragma unroll
            for (int ii = 0; ii < 8; ii++) {
                int i = w * 8 + ii;
                int d = degp[i];
                float sw0 = 0.f, sw1 = 0.f, a0 = 0.f, a1 = 0.f;
                for (int k = 0; k < d; k++) {
                    int pkt = nbrp[i * 64 + k];
                    int j = pkt & 63, e = pkt >> 8;
                    unsigned ha = *(const unsigned*)(lds + OFF_HA + j * 256 + 4 * l);
                    float2 hm = *(const float2*)(lds + OFF_HM + j * 512 + 8 * l);
                    float2 wa = *(const float2*)(lds + OFF_WAE + e * 512 + 8 * l);
                    float2 wm = *(const float2*)(lds + OFF_WME + e * 512 + 8 * l);
                    float e0 = bf2f((unsigned short)ha) + wa.x;
                    float e1 = bf2f((unsigned short)(ha >> 16)) + wa.y;
                    float w0 = __expf(e0), w1 = __expf(e1);
                    sw0 += w0; sw1 += w1;
                    a0 += w0 * (hm.x + wm.x);
                    a1 += w1 * (hm.y + wm.y);
                }
                resv[2 * ii]     = d ? a0 / sw0 + bm0 : 0.f;
                resv[2 * ii + 1] = d ? a1 / sw1 + bm1 : 0.f;
            }
        }
        __syncthreads();   // all HA/HM reads done before mg overlays them
#pragma unroll
        for (int ii = 0; ii < 8; ii++) {
            int i = w * 8 + ii;
            float r0 = resv[2 * ii], r1 = resv[2 * ii + 1];
            unsigned short h0 = f2bf(r0), h1 = f2bf(r1);
            unsigned short g0 = f2bf(r0 - bf2f(h0)), g1 = f2bf(r1 - bf2f(h1));
            int byt = (4 * l) ^ ((i & 7) << 4);
            *(unsigned*)(lds + OFF_MGH + i * 256 + byt) = (unsigned)h0 | ((unsigned)h1 << 16);
            *(unsigned*)(lds + OFF_MGL + i * 256 + byt) = (unsigned)g0 | ((unsigned)g1 << 16);
        }
        __syncthreads();

        // ===== GRU: A-frags then 4 col-groups of 32 =====
        {
            short8 mh[4], ml[4], hh2[4], hl2[4];
#pragma unroll
            for (int kb = 0; kb < 4; kb++) {
                int byt = arow * 256 + ((kb * 64 + ((l >> 4) * 16)) ^ ((arow & 7) << 4));
                mh[kb]  = *(const short8*)(lds + OFF_MGH + byt);
                ml[kb]  = *(const short8*)(lds + OFF_MGL + byt);
                hh2[kb] = *(const short8*)(lds + OFF_HHI + byt);
                hl2[kb] = *(const short8*)(lds + OFF_HLO + byt);
            }
            for (int g = 0; g < 4; g++) {
                __syncthreads();           // prior group done reading Bbuf
                for (int r2 = 0; r2 < 6; r2++) {
                    int idx = r2 * 4096 + tid * 8;
                    short8 v = *(const short8*)&pk[(64 + g * 48) * 512 + idx];
                    *(short8*)(lds + OFF_B + idx * 2) = v;
                }
                __syncthreads();
                f32x4 ar = {0,0,0,0}, az = {0,0,0,0}, ani = {0,0,0,0}, anh = {0,0,0,0};
#pragma unroll
                for (int kb = 0; kb < 8; kb++) {
                    short8 Ah = (kb < 4) ? mh[kb] : hh2[kb - 4];
                    short8 Al = (kb < 4) ? ml[kb] : hl2[kb - 4];
                    short8 Br = *(const short8*)(lds + OFF_B + (      colh8 * 8 + kb) * 1024 + l * 16);
                    short8 Bz = *(const short8*)(lds + OFF_B + (16  + colh8 * 8 + kb) * 1024 + l * 16);
                    short8 Bn = *(const short8*)(lds + OFF_B + (32  + colh8 * 8 + kb) * 1024 + l * 16);
                    ar = mfma16(Ah, Br, ar); ar = mfma16(Al, Br, ar);
                    az = mfma16(Ah, Bz, az); az = mfma16(Al, Bz, az);
                    if (kb < 4) { ani = mfma16(Ah, Bn, ani); ani = mfma16(Al, Bn, ani); }
                    else        { anh = mfma16(Ah, Bn, anh); anh = mfma16(Al, Bn, anh); }
                }
                int colh = g * 32 + colh8 * 16 + (l & 15);
                float bir = b_i[colh] + b_h[colh];
                float biz = b_i[128 + colh] + b_h[128 + colh];
                float bin = b_i[256 + colh], bhn = b_h[256 + colh];
#pragma unroll
                for (int r = 0; r < 4; r++) {
                    int row = rowb + r;
                    if (degp[row] > 0) {
                        int byt = (colh * 2) ^ ((row & 7) << 4);
                        float hold = bf2f(*(unsigned short*)(lds + OFF_HHI + row * 256 + byt))
                                   + bf2f(*(unsigned short*)(lds + OFF_HLO + row * 256 + byt));
                        float rg = sigmoidf_(ar[r] + bir);
                        float zg = sigmoidf_(az[r] + biz);
                        float ng = tanhf(ani[r] + bin + rg * (anh[r] + bhn));
                        float hn = (1.f - zg) * ng + zg * hold;
                        unsigned short h16 = f2bf(hn);
                        *(unsigned short*)(lds + OFF_HHI + row * 256 + byt) = h16;
                        *(unsigned short*)(lds + OFF_HLO + row * 256 + byt) = f2bf(hn - bf2f(h16));
                    }
                }
            }
        }
        __syncthreads();
    }

    // ===== readout =====
    {
        // stage We + Wg1 (64 KB)
        for (int r2 = 0; r2 < 8; r2++) {
            int idx = r2 * 4096 + tid * 8;
            short8 v = *(const short8*)&pk[256 * 512 + idx];
            *(short8*)(lds + OFF_B + idx * 2) = v;
        }
        // A-frags: h (LDS) and x (global f32 -> hi/lo)
        short8 hh2[4], hl2[4], xh[4], xl[4];
#pragma unroll
        for (int kb = 0; kb < 4; kb++) {
            int byt = arow * 256 + ((kb * 64 + ((l >> 4) * 16)) ^ ((arow & 7) << 4));
            hh2[kb] = *(const short8*)(lds + OFF_HHI + byt);
            hl2[kb] = *(const short8*)(lds + OFF_HLO + byt);
            const float* p = nodes + (size_t)b * 8192 + arow * 128 + kb * 32 + (l >> 4) * 8;
            short8 vh, vl;
#pragma unroll
            for (int j = 0; j < 8; j++) {
                float v = p[j];
                unsigned short hv = f2bf(v);
                vh[j] = (short)hv;
                vl[j] = (short)f2bf(v - bf2f(hv));
            }
            xh[kb] = vh; xl[kb] = vl;
        }
        __syncthreads();

        f32x4 ae[4], ag[4];
#pragma unroll
        for (int ci = 0; ci < 4; ci++) {
            int nt = colh8 + ci * 2;
            f32x4 e = {0,0,0,0}, g2 = {0,0,0,0};
#pragma unroll
            for (int kb = 0; kb < 4; kb++) {
                short8 Be = *(const short8*)(lds + OFF_B + (     nt * 4 + kb) * 1024 + l * 16);
                short8 Bg = *(const short8*)(lds + OFF_B + (32 + nt * 4 + kb) * 1024 + l * 16);
                e  = mfma16(hh2[kb], Be, e);  e  = mfma16(hl2[kb], Be, e);
                g2 = mfma16(hh2[kb], Bg, g2); g2 = mfma16(hl2[kb], Bg, g2);
            }
            ae[ci] = e; ag[ci] = g2;
        }
        __syncthreads();
        // stage Wg2 (32 KB)
        for (int r2 = 0; r2 < 4; r2++) {
            int idx = r2 * 4096 + tid * 8;
            short8 v = *(const short8*)&pk[320 * 512 + idx];
            *(short8*)(lds + OFF_B + idx * 2) = v;
        }
        __syncthreads();
#pragma unroll
        for (int ci = 0; ci < 4; ci++) {
            int nt = colh8 + ci * 2;
            f32x4 g2 = ag[ci];
#pragma unroll
            for (int kb = 0; kb < 4; kb++) {
                short8 Bg = *(const short8*)(lds + OFF_B + (nt * 4 + kb) * 1024 + l * 16);
                g2 = mfma16(xh[kb], Bg, g2); g2 = mfma16(xl[kb], Bg, g2);
            }
            ag[ci] = g2;
        }
        __syncthreads();   // Bbuf reads done; RED region (mg) is dead
        float* red = (float*)(lds + OFF_RED);
        int dmask[4];
#pragma unroll
        for (int r = 0; r < 4; r++) dmask[r] = degp[rowb + r] > 0;
#pragma unroll
        for (int ci = 0; ci < 4; ci++) {
            int nt = colh8 + ci * 2;
            int col = nt * 16 + (l & 15);
            float be = b_emb[col], bg = b_gate[col];
            float s = 0.f;
#pragma unroll
            for (int r = 0; r < 4; r++)
                if (dmask[r]) s += sigmoidf_(ag[ci][r] + bg) * (ae[ci][r] + be);
            s += __shfl_xor(s, 16);
            s += __shfl_xor(s, 32);
            if (l < 16) red[rowt * 128 + nt * 16 + l] = s;
        }
        __syncthreads();
        if (tid < 128)
            out[(size_t)b * 128 + tid] = red[tid] + red[128 + tid] + red[256 + tid] + red[384 + tid];
    }
}

// ---------------------------------------------------------------------------

extern "C" void kernel_launch(void* const* d_in, const int* in_sizes, int n_in,
                              void* d_out, int out_size, void* d_ws, size_t ws_size,
                              hipStream_t stream) {
    const float* nodes  = (const float*)d_in[0];
    const float* edges  = (const float*)d_in[1];
    const float* W_att  = (const float*)d_in[2];
    const float* W_msg  = (const float*)d_in[4];
    const float* b_msg  = (const float*)d_in[5];
    const float* W_i    = (const float*)d_in[6];
    const float* b_i    = (const float*)d_in[7];
    const float* W_h    = (const float*)d_in[8];
    const float* b_h    = (const float*)d_in[9];
    const float* W_gate = (const float*)d_in[10];
    const float* b_gate = (const float*)d_in[11];
    const float* W_emb  = (const float*)d_in[12];
    const float* b_emb  = (const float*)d_in[13];
    float* out = (float*)d_out;

    char* ws = (char*)d_ws;
    unsigned short* pkbuf = (unsigned short*)ws;  ws += (size_t)PK_TILES * 512 * 2;  // 360448
    unsigned short* nbr_g = (unsigned short*)ws;  ws += (size_t)4096 * 64 * 2;       // 524288
    int* deg_g = (int*)ws;

    prep_pack<<<PK_TILES, 64, 0, stream>>>(W_att, W_msg, W_i, W_h, W_gate, W_emb, pkbuf);
    build_adj<<<64, 512, 0, stream>>>(edges, nbr_g, deg_g);
    mpnn_main<<<64, 512, 0, stream>>>(nodes, W_att, W_msg, b_msg, b_i, b_h,
                                      b_gate, b_emb, pkbuf, nbr_g, deg_g, out);
}

// Round 4
// 70.772 us; speedup vs baseline: 5.2730x; 1.8104x over previous
//
#include <hip/hip_runtime.h>
#include <hip/hip_bf16.h>

// AggregationMPNN: B=64, N=64, E=16, H=M=OUT=128, 3 passes.
// v4: 4 blocks per graph (256 blocks x 512 thr) per pass; hidden ping-pongs
// through global f32 between pass dispatches. Each block: full P-GEMM (64x256,
// duplicated), attention+GRU for its 16 nodes. Readout partials + reduce kernel.
// NOTE: GRU n-gate keeps mg@Wi_n and h@Wh_n in SEPARATE accumulators (r gates gh_n only).

typedef __attribute__((ext_vector_type(8))) short short8;
typedef __attribute__((ext_vector_type(4))) float f32x4;

// pk tile map (1 KB tiles; k=kb*32+(l>>4)*8+j, n=nt*16+(l&15)):
//   [0,64)    Wam [nt16][kb4]
//   [64,256)  GRU [grp4][gate3][nt2][kb8]; col = gate*128 + grp*32 + nt*16 + nb
//             gate 0/1: k<128->Wi, k>=128->Wh (K=256 joint).  gate 2 (n):
//             kb0-3 = Wi_n rows (k=kb*32+kk), kb4-7 = Wh_n rows (k-128).
//   [256,288) We  [nt8][kb4]
//   [288,352) Wg  [nt8][kb8] (k<128 h-rows, k>=128 x-rows)
#define PK_TILES 352

#define OFF_HHI 0
#define OFF_HLO 16384
#define OFF_HA  32768
#define OFF_MGH 32768
#define OFF_MGL 36864
#define OFF_GB  40960      // f32: r[16][32] @ +0, z @ +2048, ni @ +4096, nh @ +6144 (8 KB)
#define OFF_HM  49152
#define OFF_WB  81920
#define OFF_WAE 81920
#define OFF_WME 90112
#define OFF_NBR 98304
#define OFF_DEG 147456
#define LDS_BYTES 147520

__device__ __forceinline__ unsigned short f2bf(float x) {
    unsigned u = __float_as_uint(x);
    u += 0x7FFF + ((u >> 16) & 1);
    return (unsigned short)(u >> 16);
}
__device__ __forceinline__ float bf2f(unsigned short h) {
    return __uint_as_float((unsigned)h << 16);
}
__device__ __forceinline__ float sigmoidf_(float x) { return 1.f / (1.f + __expf(-x)); }
__device__ __forceinline__ f32x4 mfma16(short8 a, short8 b, f32x4 c) {
    return __builtin_amdgcn_mfma_f32_16x16x32_bf16(a, b, c, 0, 0, 0);
}

__global__ __launch_bounds__(512) void fused_prep(
    const float* __restrict__ Wa, const float* __restrict__ Wm,
    const float* __restrict__ Wi, const float* __restrict__ Wh,
    const float* __restrict__ Wg, const float* __restrict__ We,
    const float* __restrict__ edges,
    unsigned short* __restrict__ pk, unsigned short* __restrict__ nbr_g,
    int* __restrict__ deg_g)
{
    int bid = blockIdx.x;
    if (bid < 44) {
        int t = (bid << 3) + (threadIdx.x >> 6);
        int l = threadIdx.x & 63;
        short8 v8;
#pragma unroll
        for (int j = 0; j < 8; j++) {
            int kk = (l >> 4) * 8 + j;
            int nb = l & 15;
            float x;
            if (t < 64) {
                int nt = t >> 2, kb = t & 3;
                int k = kb * 32 + kk, n = nt * 16 + nb;
                x = (n < 128) ? Wa[k * 128 + n] : Wm[k * 128 + n - 128];
            } else if (t < 256) {
                int u = t - 64;
                int g = u / 48, r1 = u % 48;
                int gate = r1 >> 4, v = r1 & 15;
                int nt = v >> 3, kb = v & 7;
                int k = kb * 32 + kk;
                int col = g * 32 + nt * 16 + nb;
                if (gate == 0)      x = (k < 128) ? Wi[k * 384 + col] : Wh[(k - 128) * 384 + col];
                else if (gate == 1) x = (k < 128) ? Wi[k * 384 + 128 + col] : Wh[(k - 128) * 384 + 128 + col];
                else                x = (k < 128) ? Wi[k * 384 + 256 + col] : Wh[(k - 128) * 384 + 256 + col];
            } else if (t < 288) {
                int u = t - 256; int nt = u >> 2, kb = u & 3;
                x = We[(kb * 32 + kk) * 128 + nt * 16 + nb];
            } else {
                int u = t - 288; int nt = u >> 3, kb = u & 7;
                x = Wg[(kb * 32 + kk) * 128 + nt * 16 + nb];
            }
            v8[j] = (short)f2bf(x);
        }
        *(short8*)&pk[(size_t)t * 512 + l * 8] = v8;
    } else {
        int b = bid - 44;
        int w = threadIdx.x >> 6, l = threadIdx.x & 63;
        for (int ii = 0; ii < 8; ii++) {
            int i = w * 8 + ii;
            int n = b * 64 + i;
            const float4* ep = (const float4*)&edges[(size_t)(n * 64 + l) * 16];
            int et = -1;
#pragma unroll
            for (int q = 0; q < 4; q++) {
                float4 v = ep[q];
                if (v.x > 0.5f) et = q * 4 + 0;
                if (v.y > 0.5f) et = q * 4 + 1;
                if (v.z > 0.5f) et = q * 4 + 2;
                if (v.w > 0.5f) et = q * 4 + 3;
            }
            unsigned long long mask = __ballot(et >= 0);
            int pos = __popcll(mask & ((1ull << l) - 1ull));
            if (et >= 0) nbr_g[(size_t)n * 64 + pos] = (unsigned short)(l | (et << 8));
            if (l == 0) deg_g[n] = (int)__popcll(mask);
        }
    }
}

__global__ __launch_bounds__(512, 2) void pass_kernel(
    const float* __restrict__ hin, float* __restrict__ hout,
    const float* __restrict__ nodes, const float* __restrict__ W_att,
    const float* __restrict__ W_msg, const float* __restrict__ b_msg,
    const float* __restrict__ b_i, const float* __restrict__ b_h,
    const float* __restrict__ b_gate, const float* __restrict__ b_emb,
    const unsigned short* __restrict__ pk, const unsigned short* __restrict__ nbr_g,
    const int* __restrict__ deg_g, float* __restrict__ part, int last)
{
    __shared__ __align__(16) char lds[LDS_BYTES];
    const int tid = threadIdx.x;
    const int w = tid >> 6, l = tid & 63;
    const int b = blockIdx.x >> 2, sub = blockIdx.x & 3;
    int* degp = (int*)(lds + OFF_DEG);

    for (int idx = tid; idx < 8192; idx += 512) {
        int row = idx >> 7, col = idx & 127;
        float v = hin[(size_t)b * 8192 + idx];
        unsigned short hh = f2bf(v);
        int byt = (col * 2) ^ ((row & 7) << 4);
        *(unsigned short*)(lds + OFF_HHI + row * 256 + byt) = hh;
        *(unsigned short*)(lds + OFF_HLO + row * 256 + byt) = f2bf(v - bf2f(hh));
    }
    if (tid < 16) degp[tid] = deg_g[b * 64 + sub * 16 + tid];
    for (int r2 = 0; r2 < 8; r2++) {
        int idx = r2 * 4096 + tid * 8;
        *(short8*)(lds + OFF_WB + idx * 2) = *(const short8*)&pk[idx];
    }
    __syncthreads();

    // ===== P-GEMM (64x256, duplicated) =====
    {
        const int rowt = w & 3, colh = w >> 2;
        const int arow = rowt * 16 + (l & 15);
        const int rowb = rowt * 16 + (l >> 4) * 4;
        short8 ah[4], al[4];
#pragma unroll
        for (int kb = 0; kb < 4; kb++) {
            int byt = arow * 256 + ((kb * 64 + ((l >> 4) * 16)) ^ ((arow & 7) << 4));
            ah[kb] = *(const short8*)(lds + OFF_HHI + byt);
            al[kb] = *(const short8*)(lds + OFF_HLO + byt);
        }
#pragma unroll
        for (int nt2 = 0; nt2 < 8; nt2++) {
            int nt = colh * 8 + nt2;
            f32x4 acc = {0.f, 0.f, 0.f, 0.f};
#pragma unroll
            for (int kb = 0; kb < 4; kb++) {
                short8 bf = *(const short8*)(lds + OFF_WB + (nt * 4 + kb) * 1024 + l * 16);
                acc = mfma16(ah[kb], bf, acc);
                acc = mfma16(al[kb], bf, acc);
            }
            int col = nt * 16 + (l & 15);
            if (nt < 8) {
#pragma unroll
                for (int r = 0; r < 4; r++)
                    *(unsigned short*)(lds + OFF_HA + (rowb + r) * 256 + col * 2) = f2bf(acc[r]);
            } else {
#pragma unroll
                for (int r = 0; r < 4; r++)
                    *(float*)(lds + OFF_HM + (rowb + r) * 512 + (col - 128) * 4) = acc[r];
            }
        }
    }
    __syncthreads();

    *(float4*)(lds + OFF_WAE + tid * 16) = *(const float4*)&W_att[16384 + tid * 4];
    *(float4*)(lds + OFF_WME + tid * 16) = *(const float4*)&W_msg[16384 + tid * 4];
    *(unsigned*)(lds + OFF_NBR + tid * 4) =
        *(const unsigned*)&nbr_g[(size_t)(b * 64 + sub * 16) * 64 + tid * 2];
    __syncthreads();

    // ===== attention: wave w -> local rows 2w, 2w+1 =====
    const float bm0 = b_msg[2 * l], bm1 = b_msg[2 * l + 1];
    float resv[4];
    {
        const unsigned short* nbrp = (const unsigned short*)(lds + OFF_NBR);
#pragma unroll
        for (int rr = 0; rr < 2; rr++) {
            int iloc = w * 2 + rr;
            int d = degp[iloc];
            float sw0 = 0.f, sw1 = 0.f, a0 = 0.f, a1 = 0.f;
            for (int k = 0; k < d; k++) {
                int pkt = nbrp[iloc * 64 + k];
                int j = pkt & 63, e = pkt >> 8;
                unsigned ha = *(const unsigned*)(lds + OFF_HA + j * 256 + 4 * l);
                float2 hm = *(const float2*)(lds + OFF_HM + j * 512 + 8 * l);
                float2 wa = *(const float2*)(lds + OFF_WAE + e * 512 + 8 * l);
                float2 wm = *(const float2*)(lds + OFF_WME + e * 512 + 8 * l);
                float e0 = bf2f((unsigned short)ha) + wa.x;
                float e1 = bf2f((unsigned short)(ha >> 16)) + wa.y;
                float w0 = __expf(e0), w1 = __expf(e1);
                sw0 += w0; sw1 += w1;
                a0 += w0 * (hm.x + wm.x);
                a1 += w1 * (hm.y + wm.y);
            }
            resv[2 * rr]     = d ? a0 / sw0 + bm0 : 0.f;
            resv[2 * rr + 1] = d ? a1 / sw1 + bm1 : 0.f;
        }
    }
    __syncthreads();
#pragma unroll
    for (int rr = 0; rr < 2; rr++) {
        int iloc = w * 2 + rr;
        float r0 = resv[2 * rr], r1 = resv[2 * rr + 1];
        unsigned short h0 = f2bf(r0), h1 = f2bf(r1);
        unsigned short g0 = f2bf(r0 - bf2f(h0)), g1 = f2bf(r1 - bf2f(h1));
        int byt = (4 * l) ^ ((iloc & 7) << 4);
        *(unsigned*)(lds + OFF_MGH + iloc * 256 + byt) = (unsigned)h0 | ((unsigned)h1 << 16);
        *(unsigned*)(lds + OFF_MGL + iloc * 256 + byt) = (unsigned)g0 | ((unsigned)g1 << 16);
    }
    __syncthreads();

    // ===== GRU (M=16 local rows) =====
    {
        const int lr = l & 15;
        const int grow = sub * 16 + lr;
        short8 mh[4], ml[4], hh2[4], hl2[4];
#pragma unroll
        for (int kb = 0; kb < 4; kb++) {
            int sw2 = kb * 64 + ((l >> 4) * 16);
            mh[kb]  = *(const short8*)(lds + OFF_MGH + lr * 256 + (sw2 ^ ((lr & 7) << 4)));
            ml[kb]  = *(const short8*)(lds + OFF_MGL + lr * 256 + (sw2 ^ ((lr & 7) << 4)));
            hh2[kb] = *(const short8*)(lds + OFF_HHI + grow * 256 + (sw2 ^ ((grow & 7) << 4)));
            hl2[kb] = *(const short8*)(lds + OFF_HLO + grow * 256 + (sw2 ^ ((grow & 7) << 4)));
        }
        for (int g = 0; g < 4; g++) {
            for (int r2 = 0; r2 < 6; r2++) {
                int idx = r2 * 4096 + tid * 8;
                *(short8*)(lds + OFF_WB + idx * 2) =
                    *(const short8*)&pk[(size_t)(64 + g * 48) * 512 + idx];
            }
            __syncthreads();
            if (w < 6) {
                int gate = w >> 1, ct = w & 1;
                int row0 = (l >> 4) * 4, c = ct * 16 + (l & 15);
                if (gate < 2) {                     // r or z: K=256 joint
                    f32x4 acc = {0.f, 0.f, 0.f, 0.f};
#pragma unroll
                    for (int kb = 0; kb < 8; kb++) {
                        short8 Ah = (kb < 4) ? mh[kb] : hh2[kb - 4];
                        short8 Al = (kb < 4) ? ml[kb] : hl2[kb - 4];
                        short8 Bf = *(const short8*)(lds + OFF_WB + (gate * 16 + ct * 8 + kb) * 1024 + l * 16);
                        acc = mfma16(Ah, Bf, acc);
                        acc = mfma16(Al, Bf, acc);
                    }
#pragma unroll
                    for (int r = 0; r < 4; r++)
                        *(float*)(lds + OFF_GB + gate * 2048 + (row0 + r) * 128 + c * 4) = acc[r];
                } else {                            // n: ni (mg@Wi_n), nh (h@Wh_n) separate
                    f32x4 ani = {0.f, 0.f, 0.f, 0.f}, anh = {0.f, 0.f, 0.f, 0.f};
#pragma unroll
                    for (int kb = 0; kb < 4; kb++) {
                        short8 Bi = *(const short8*)(lds + OFF_WB + (32 + ct * 8 + kb) * 1024 + l * 16);
                        short8 Bh = *(const short8*)(lds + OFF_WB + (32 + ct * 8 + 4 + kb) * 1024 + l * 16);
                        ani = mfma16(mh[kb], Bi, ani);  ani = mfma16(ml[kb], Bi, ani);
                        anh = mfma16(hh2[kb], Bh, anh); anh = mfma16(hl2[kb], Bh, anh);
                    }
#pragma unroll
                    for (int r = 0; r < 4; r++) {
                        *(float*)(lds + OFF_GB + 4096 + (row0 + r) * 128 + c * 4) = ani[r];
                        *(float*)(lds + OFF_GB + 6144 + (row0 + r) * 128 + c * 4) = anh[r];
                    }
                }
            }
            __syncthreads();
            {
                int row = tid >> 5, c32 = tid & 31;
                int col = g * 32 + c32;
                int gr = sub * 16 + row;
                int byt = (col * 2) ^ ((gr & 7) << 4);
                float hold = bf2f(*(unsigned short*)(lds + OFF_HHI + gr * 256 + byt))
                           + bf2f(*(unsigned short*)(lds + OFF_HLO + gr * 256 + byt));
                float hn = hold;
                if (degp[row] > 0) {
                    float pr = *(float*)(lds + OFF_GB +        row * 128 + c32 * 4);
                    float pz = *(float*)(lds + OFF_GB + 2048 + row * 128 + c32 * 4);
                    float ni = *(float*)(lds + OFF_GB + 4096 + row * 128 + c32 * 4);
                    float nh = *(float*)(lds + OFF_GB + 6144 + row * 128 + c32 * 4);
                    float rg = sigmoidf_(pr + b_i[col] + b_h[col]);
                    float zg = sigmoidf_(pz + b_i[128 + col] + b_h[128 + col]);
                    float ng = tanhf(ni + b_i[256 + col] + rg * (nh + b_h[256 + col]));
                    hn = (1.f - zg) * ng + zg * hold;
                }
                hout[(size_t)(b * 64 + gr) * 128 + col] = hn;
                unsigned short h16 = f2bf(hn);
                __syncthreads();   // hold reads done across threads before overwrite
                *(unsigned short*)(lds + OFF_HHI + gr * 256 + byt) = h16;
                *(unsigned short*)(lds + OFF_HLO + gr * 256 + byt) = f2bf(hn - bf2f(h16));
            }
            __syncthreads();
        }
    }

    // ===== readout (last pass only) =====
    if (last) {
        __syncthreads();
        for (int r2 = 0; r2 < 12; r2++) {
            int idx = r2 * 4096 + tid * 8;
            *(short8*)(lds + OFF_HM + idx * 2) = *(const short8*)&pk[131072 + idx];
        }
        const int lr = l & 15;
        const int grow = sub * 16 + lr;
        short8 hh2[4], hl2[4], xh[4], xl[4];
#pragma unroll
        for (int kb = 0; kb < 4; kb++) {
            int sw2 = kb * 64 + ((l >> 4) * 16);
            hh2[kb] = *(const short8*)(lds + OFF_HHI + grow * 256 + (sw2 ^ ((grow & 7) << 4)));
            hl2[kb] = *(const short8*)(lds + OFF_HLO + grow * 256 + (sw2 ^ ((grow & 7) << 4)));
            const float* p = nodes + (size_t)(b * 64 + grow) * 128 + kb * 32 + (l >> 4) * 8;
            short8 vh, vl;
#pragma unroll
            for (int j = 0; j < 8; j++) {
                float v = p[j];
                unsigned short hv = f2bf(v);
                vh[j] = (short)hv;
                vl[j] = (short)f2bf(v - bf2f(hv));
            }
            xh[kb] = vh; xl[kb] = vl;
        }
        __syncthreads();
        int nt = w;
        int col = nt * 16 + (l & 15);
        f32x4 ae = {0.f, 0.f, 0.f, 0.f}, ag = {0.f, 0.f, 0.f, 0.f};
#pragma unroll
        for (int kb = 0; kb < 4; kb++) {
            short8 Be = *(const short8*)(lds + OFF_HM + (nt * 4 + kb) * 1024 + l * 16);
            ae = mfma16(hh2[kb], Be, ae);
            ae = mfma16(hl2[kb], Be, ae);
        }
#pragma unroll
        for (int kb = 0; kb < 8; kb++) {
            short8 Ah = (kb < 4) ? hh2[kb] : xh[kb - 4];
            short8 Al = (kb < 4) ? hl2[kb] : xl[kb - 4];
            short8 Bg = *(const short8*)(lds + OFF_HM + (32 + nt * 8 + kb) * 1024 + l * 16);
            ag = mfma16(Ah, Bg, ag);
            ag = mfma16(Al, Bg, ag);
        }
        float be = b_emb[col], bg = b_gate[col];
        float s = 0.f;
#pragma unroll
        for (int r = 0; r < 4; r++)
            if (degp[(l >> 4) * 4 + r] > 0)
                s += sigmoidf_(ag[r] + bg) * (ae[r] + be);
        s += __shfl_xor(s, 16);
        s += __shfl_xor(s, 32);
        if (l < 16) part[(size_t)blockIdx.x * 128 + nt * 16 + l] = s;
    }
}

__global__ __launch_bounds__(256) void reduce_out(
    const float* __restrict__ part, float* __restrict__ out)
{
    int idx = blockIdx.x * 256 + threadIdx.x;   // 8192
    int b = idx >> 7, c = idx & 127;
    out[idx] = part[(size_t)(b * 4 + 0) * 128 + c] + part[(size_t)(b * 4 + 1) * 128 + c]
             + part[(size_t)(b * 4 + 2) * 128 + c] + part[(size_t)(b * 4 + 3) * 128 + c];
}

extern "C" void kernel_launch(void* const* d_in, const int* in_sizes, int n_in,
                              void* d_out, int out_size, void* d_ws, size_t ws_size,
                              hipStream_t stream) {
    const float* nodes  = (const float*)d_in[0];
    const float* edges  = (const float*)d_in[1];
    const float* W_att  = (const float*)d_in[2];
    const float* W_msg  = (const float*)d_in[4];
    const float* b_msg  = (const float*)d_in[5];
    const float* W_i    = (const float*)d_in[6];
    const float* b_i    = (const float*)d_in[7];
    const float* W_h    = (const float*)d_in[8];
    const float* b_h    = (const float*)d_in[9];
    const float* W_gate = (const float*)d_in[10];
    const float* b_gate = (const float*)d_in[11];
    const float* W_emb  = (const float*)d_in[12];
    const float* b_emb  = (const float*)d_in[13];
    float* out = (float*)d_out;

    char* ws = (char*)d_ws;
    unsigned short* pk    = (unsigned short*)ws; ws += (size_t)PK_TILES * 512 * 2;  // 352 KB
    unsigned short* nbr_g = (unsigned short*)ws; ws += (size_t)4096 * 64 * 2;       // 512 KB
    int*   deg_g = (int*)ws;   ws += 4096 * 4;                                      // 16 KB
    float* hid0  = (float*)ws; ws += (size_t)4096 * 128 * 4;                        // 2 MB
    float* hid1  = (float*)ws; ws += (size_t)4096 * 128 * 4;                        // 2 MB
    float* part  = (float*)ws; ws += (size_t)256 * 128 * 4;                         // 128 KB

    fused_prep<<<108, 512, 0, stream>>>(W_att, W_msg, W_i, W_h, W_gate, W_emb,
                                        edges, pk, nbr_g, deg_g);
    pass_kernel<<<256, 512, 0, stream>>>(nodes, hid0, nodes, W_att, W_msg, b_msg,
                                         b_i, b_h, b_gate, b_emb, pk, nbr_g, deg_g, part, 0);
    pass_kernel<<<256, 512, 0, stream>>>(hid0, hid1, nodes, W_att, W_msg, b_msg,
                                         b_i, b_h, b_gate, b_emb, pk, nbr_g, deg_g, part, 0);
    pass_kernel<<<256, 512, 0, stream>>>(hid1, hid0, nodes, W_att, W_msg, b_msg,
                                         b_i, b_h, b_gate, b_emb, pk, nbr_g, deg_g, part, 1);
    reduce_out<<<32, 256, 0, stream>>>(part, out);
}

// Round 6
// 53.443 us; speedup vs baseline: 6.9828x; 1.3243x over previous
//
#include <hip/hip_runtime.h>
#include <hip/hip_bf16.h>

// AggregationMPNN: B=64, N=64, E=16, H=M=OUT=128, 3 passes.
// v6 = v5 with the WaE/WmE load-loop overrun fixed (it<2, not it<4).
// - 4 blocks/graph x 3 pass-dispatches (h ping-pong in global f32)
// - GRU/readout weight fragments read DIRECTLY global->VGPR (zero reuse -> no LDS staging)
// - GRU: wave w owns output cols [w*16, w*16+16) for ALL gates (no LDS gate handoff)
// - one barrier after all concurrent start loads; ~5 barriers/pass total.

typedef __attribute__((ext_vector_type(8))) short short8;
typedef __attribute__((ext_vector_type(4))) float f32x4;

// pk tile map (1 KB tiles; fragment: lane l, j: W[k=kb*32+(l>>4)*8+j][n=nt*16+(l&15)]):
//   [0,64)    Wam [nt16][kb4]
//   [64,256)  GRU [grp4][gate3][nt2][kb8]; col = grp*32 + nt*16 + nb (+gate*128)
//             gate 0/1: kb0-7 over K=256 ([Wi;Wh]). gate 2: kb0-3 Wi_n, kb4-7 Wh_n.
//   [256,288) We  [nt8][kb4]
//   [288,352) Wg  [nt8][kb8] (kb0-3 h-rows, kb4-7 x-rows)
#define PK_TILES 352

#define OFF_HHI 0          // ushort[64][128] swizzled (16 KB)
#define OFF_HLO 16384      // (16 KB)
#define OFF_HA  32768      // bf16 [64][128] linear (16 KB); overlay: mg hi/lo below
#define OFF_MGH 32768      // ushort[16][128] swizzled (4 KB)
#define OFF_MGL 36864      // (4 KB)
#define OFF_HM  49152      // f32 [64][128] linear (32 KB)
#define OFF_WB  81920      // Wam staging (64 KB)
#define OFF_WAE 147456     // bf16-pair u32[16*64] (4 KB)
#define OFF_WME 151552     // (4 KB)
#define OFF_NBR 155648     // ushort[16][64] (2 KB)
#define OFF_DEG 157696     // int[16]
#define LDS_BYTES 157760

__device__ __forceinline__ unsigned short f2bf(float x) {
    unsigned u = __float_as_uint(x);
    u += 0x7FFF + ((u >> 16) & 1);
    return (unsigned short)(u >> 16);
}
__device__ __forceinline__ float bf2f(unsigned short h) {
    return __uint_as_float((unsigned)h << 16);
}
__device__ __forceinline__ float sigmoidf_(float x) { return 1.f / (1.f + __expf(-x)); }
__device__ __forceinline__ f32x4 mfma16(short8 a, short8 b, f32x4 c) {
    return __builtin_amdgcn_mfma_f32_16x16x32_bf16(a, b, c, 0, 0, 0);
}

__global__ __launch_bounds__(512) void fused_prep(
    const float* __restrict__ Wa, const float* __restrict__ Wm,
    const float* __restrict__ Wi, const float* __restrict__ Wh,
    const float* __restrict__ Wg, const float* __restrict__ We,
    const float* __restrict__ edges,
    unsigned short* __restrict__ pk, unsigned short* __restrict__ nbr_g,
    int* __restrict__ deg_g)
{
    int bid = blockIdx.x;
    if (bid < 44) {
        int t = (bid << 3) + (threadIdx.x >> 6);
        int l = threadIdx.x & 63;
        short8 v8;
#pragma unroll
        for (int j = 0; j < 8; j++) {
            int kk = (l >> 4) * 8 + j;
            int nb = l & 15;
            float x;
            if (t < 64) {
                int nt = t >> 2, kb = t & 3;
                int k = kb * 32 + kk, n = nt * 16 + nb;
                x = (n < 128) ? Wa[k * 128 + n] : Wm[k * 128 + n - 128];
            } else if (t < 256) {
                int u = t - 64;
                int g = u / 48, r1 = u % 48;
                int gate = r1 >> 4, v = r1 & 15;
                int nt = v >> 3, kb = v & 7;
                int k = kb * 32 + kk;
                int col = g * 32 + nt * 16 + nb;
                if (gate == 0)      x = (k < 128) ? Wi[k * 384 + col] : Wh[(k - 128) * 384 + col];
                else if (gate == 1) x = (k < 128) ? Wi[k * 384 + 128 + col] : Wh[(k - 128) * 384 + 128 + col];
                else                x = (k < 128) ? Wi[k * 384 + 256 + col] : Wh[(k - 128) * 384 + 256 + col];
            } else if (t < 288) {
                int u = t - 256; int nt = u >> 2, kb = u & 3;
                x = We[(kb * 32 + kk) * 128 + nt * 16 + nb];
            } else {
                int u = t - 288; int nt = u >> 3, kb = u & 7;
                x = Wg[(kb * 32 + kk) * 128 + nt * 16 + nb];
            }
            v8[j] = (short)f2bf(x);
        }
        *(short8*)&pk[(size_t)t * 512 + l * 8] = v8;
    } else {
        int b = bid - 44;
        int w = threadIdx.x >> 6, l = threadIdx.x & 63;
        for (int ii = 0; ii < 8; ii++) {
            int i = w * 8 + ii;
            int n = b * 64 + i;
            const float4* ep = (const float4*)&edges[(size_t)(n * 64 + l) * 16];
            int et = -1;
#pragma unroll
            for (int q = 0; q < 4; q++) {
                float4 v = ep[q];
                if (v.x > 0.5f) et = q * 4 + 0;
                if (v.y > 0.5f) et = q * 4 + 1;
                if (v.z > 0.5f) et = q * 4 + 2;
                if (v.w > 0.5f) et = q * 4 + 3;
            }
            unsigned long long mask = __ballot(et >= 0);
            int pos = __popcll(mask & ((1ull << l) - 1ull));
            if (et >= 0) nbr_g[(size_t)n * 64 + pos] = (unsigned short)(l | (et << 8));
            if (l == 0) deg_g[n] = (int)__popcll(mask);
        }
    }
}

__global__ __launch_bounds__(512, 2) void pass_kernel(
    const float* __restrict__ hin, float* __restrict__ hout,
    const float* __restrict__ nodes, const float* __restrict__ W_att,
    const float* __restrict__ W_msg, const float* __restrict__ b_msg,
    const float* __restrict__ b_i, const float* __restrict__ b_h,
    const float* __restrict__ b_gate, const float* __restrict__ b_emb,
    const unsigned short* __restrict__ pk, const unsigned short* __restrict__ nbr_g,
    const int* __restrict__ deg_g, float* __restrict__ part, int last)
{
    __shared__ __align__(16) char lds[LDS_BYTES];
    const int tid = threadIdx.x;
    const int w = tid >> 6, l = tid & 63;
    const int b = blockIdx.x >> 2, sub = blockIdx.x & 3;
    int* degp = (int*)(lds + OFF_DEG);

    // ---- concurrent start loads: h(32KB), Wam(64KB), WaE/WmE, nbr, deg, biases ----
    const int hrow = tid >> 3;
    const int hc0 = (tid & 7) * 16;
    float fv[16];
    {
        const float4* hp = (const float4*)&hin[(size_t)b * 8192 + hrow * 128 + hc0];
#pragma unroll
        for (int q = 0; q < 4; q++) *(float4*)&fv[q * 4] = hp[q];
    }
    short8 wamv[8];
#pragma unroll
    for (int r2 = 0; r2 < 8; r2++)
        wamv[r2] = *(const short8*)&pk[r2 * 4096 + tid * 8];
    // Edge-row tables: 16 rows x 128 ch = 2048 floats each -> 1024 bf16-pairs (it<2!)
    float2 waev[2], wmev[2];
#pragma unroll
    for (int it = 0; it < 2; it++) {
        waev[it] = *(const float2*)&W_att[16384 + (tid + it * 512) * 2];
        wmev[it] = *(const float2*)&W_msg[16384 + (tid + it * 512) * 2];
    }
    unsigned nbrv = *(const unsigned*)&nbr_g[(size_t)(b * 64 + sub * 16) * 64 + tid * 2];
    const int colw = w * 16 + (l & 15);
    const float bir = b_i[colw] + b_h[colw];
    const float biz = b_i[128 + colw] + b_h[128 + colw];
    const float bin = b_i[256 + colw];
    const float bhn = b_h[256 + colw];
    const float bm0 = b_msg[2 * l], bm1 = b_msg[2 * l + 1];
    if (tid < 16) degp[tid] = deg_g[b * 64 + sub * 16 + tid];

    // stores
#pragma unroll
    for (int q = 0; q < 2; q++) {
        short8 sh, sl;
#pragma unroll
        for (int j = 0; j < 8; j++) {
            float v = fv[q * 8 + j];
            unsigned short hh = f2bf(v);
            sh[j] = (short)hh;
            sl[j] = (short)f2bf(v - bf2f(hh));
        }
        int byt = (hc0 * 2 + q * 16) ^ ((hrow & 7) << 4);
        *(short8*)(lds + OFF_HHI + hrow * 256 + byt) = sh;
        *(short8*)(lds + OFF_HLO + hrow * 256 + byt) = sl;
    }
#pragma unroll
    for (int r2 = 0; r2 < 8; r2++)
        *(short8*)(lds + OFF_WB + (r2 * 4096 + tid * 8) * 2) = wamv[r2];
#pragma unroll
    for (int it = 0; it < 2; it++) {
        int idx = tid + it * 512;
        *(unsigned*)(lds + OFF_WAE + idx * 4) =
            (unsigned)f2bf(waev[it].x) | ((unsigned)f2bf(waev[it].y) << 16);
        *(unsigned*)(lds + OFF_WME + idx * 4) =
            (unsigned)f2bf(wmev[it].x) | ((unsigned)f2bf(wmev[it].y) << 16);
    }
    *(unsigned*)(lds + OFF_NBR + tid * 4) = nbrv;
    __syncthreads();

    // ===== P-GEMM: [HA|HM] = h @ Wam (64x256, duplicated per block) =====
    {
        const int rowt = w & 3, colh = w >> 2;
        const int arow = rowt * 16 + (l & 15);
        const int rowb = rowt * 16 + (l >> 4) * 4;
        short8 ah[4], al[4];
#pragma unroll
        for (int kb = 0; kb < 4; kb++) {
            int byt = arow * 256 + ((kb * 64 + ((l >> 4) * 16)) ^ ((arow & 7) << 4));
            ah[kb] = *(const short8*)(lds + OFF_HHI + byt);
            al[kb] = *(const short8*)(lds + OFF_HLO + byt);
        }
#pragma unroll
        for (int nt2 = 0; nt2 < 8; nt2++) {
            int nt = colh * 8 + nt2;
            f32x4 acc = {0.f, 0.f, 0.f, 0.f};
#pragma unroll
            for (int kb = 0; kb < 4; kb++) {
                short8 bf = *(const short8*)(lds + OFF_WB + (nt * 4 + kb) * 1024 + l * 16);
                acc = mfma16(ah[kb], bf, acc);
                acc = mfma16(al[kb], bf, acc);
            }
            int col = nt * 16 + (l & 15);
            if (nt < 8) {
#pragma unroll
                for (int r = 0; r < 4; r++)
                    *(unsigned short*)(lds + OFF_HA + (rowb + r) * 256 + col * 2) = f2bf(acc[r]);
            } else {
#pragma unroll
                for (int r = 0; r < 4; r++)
                    *(float*)(lds + OFF_HM + (rowb + r) * 512 + (col - 128) * 4) = acc[r];
            }
        }
    }
    __syncthreads();

    // ===== attention: wave w -> local rows 2w, 2w+1; 2 channels/lane =====
    float resv[4];
    {
        const unsigned short* nbrp = (const unsigned short*)(lds + OFF_NBR);
#pragma unroll
        for (int rr = 0; rr < 2; rr++) {
            int iloc = w * 2 + rr;
            int d = degp[iloc];
            float sw0 = 0.f, sw1 = 0.f, a0 = 0.f, a1 = 0.f;
            for (int k = 0; k < d; k++) {
                int pkt = nbrp[iloc * 64 + k];
                int j = pkt & 63, e = pkt >> 8;
                unsigned ha = *(const unsigned*)(lds + OFF_HA + j * 256 + 4 * l);
                float2 hm = *(const float2*)(lds + OFF_HM + j * 512 + 8 * l);
                unsigned wa2 = *(const unsigned*)(lds + OFF_WAE + (e * 64 + l) * 4);
                unsigned wm2 = *(const unsigned*)(lds + OFF_WME + (e * 64 + l) * 4);
                float e0 = bf2f((unsigned short)ha) + bf2f((unsigned short)wa2);
                float e1 = bf2f((unsigned short)(ha >> 16)) + bf2f((unsigned short)(wa2 >> 16));
                float w0 = __expf(e0), w1 = __expf(e1);
                sw0 += w0; sw1 += w1;
                a0 += w0 * (hm.x + bf2f((unsigned short)wm2));
                a1 += w1 * (hm.y + bf2f((unsigned short)(wm2 >> 16)));
            }
            resv[2 * rr]     = d ? a0 / sw0 + bm0 : 0.f;
            resv[2 * rr + 1] = d ? a1 / sw1 + bm1 : 0.f;
        }
    }
    __syncthreads();   // HA/HM reads done before mg overlays HA
#pragma unroll
    for (int rr = 0; rr < 2; rr++) {
        int iloc = w * 2 + rr;
        float r0 = resv[2 * rr], r1 = resv[2 * rr + 1];
        unsigned short h0 = f2bf(r0), h1 = f2bf(r1);
        unsigned short g0 = f2bf(r0 - bf2f(h0)), g1 = f2bf(r1 - bf2f(h1));
        int byt = (4 * l) ^ ((iloc & 7) << 4);
        *(unsigned*)(lds + OFF_MGH + iloc * 256 + byt) = (unsigned)h0 | ((unsigned)h1 << 16);
        *(unsigned*)(lds + OFF_MGL + iloc * 256 + byt) = (unsigned)g0 | ((unsigned)g1 << 16);
    }
    __syncthreads();

    // ===== GRU: wave w owns cols [w*16, w*16+16) for all gates; B direct from global =====
    {
        const int gbase = 64 + (w >> 1) * 48;
        const int ntc8 = (w & 1) * 8;
        short8 br[8], bz[8], bni[4], bnh[4];
#pragma unroll
        for (int kb = 0; kb < 8; kb++) {
            br[kb] = *(const short8*)&pk[(size_t)(gbase + ntc8 + kb) * 512 + l * 8];
            bz[kb] = *(const short8*)&pk[(size_t)(gbase + 16 + ntc8 + kb) * 512 + l * 8];
        }
#pragma unroll
        for (int kb = 0; kb < 4; kb++) {
            bni[kb] = *(const short8*)&pk[(size_t)(gbase + 32 + ntc8 + kb) * 512 + l * 8];
            bnh[kb] = *(const short8*)&pk[(size_t)(gbase + 32 + ntc8 + 4 + kb) * 512 + l * 8];
        }
        const int lr = l & 15;
        const int grow = sub * 16 + lr;
        short8 mh[4], ml[4], hh2[4], hl2[4];
#pragma unroll
        for (int kb = 0; kb < 4; kb++) {
            int sw2 = kb * 64 + ((l >> 4) * 16);
            mh[kb]  = *(const short8*)(lds + OFF_MGH + lr * 256 + (sw2 ^ ((lr & 7) << 4)));
            ml[kb]  = *(const short8*)(lds + OFF_MGL + lr * 256 + (sw2 ^ ((lr & 7) << 4)));
            hh2[kb] = *(const short8*)(lds + OFF_HHI + grow * 256 + (sw2 ^ ((grow & 7) << 4)));
            hl2[kb] = *(const short8*)(lds + OFF_HLO + grow * 256 + (sw2 ^ ((grow & 7) << 4)));
        }
        f32x4 ar = {0,0,0,0}, az = {0,0,0,0}, ani = {0,0,0,0}, anh = {0,0,0,0};
#pragma unroll
        for (int kb = 0; kb < 4; kb++) {
            ar  = mfma16(mh[kb], br[kb], ar);   ar  = mfma16(ml[kb], br[kb], ar);
            az  = mfma16(mh[kb], bz[kb], az);   az  = mfma16(ml[kb], bz[kb], az);
            ani = mfma16(mh[kb], bni[kb], ani); ani = mfma16(ml[kb], bni[kb], ani);
            anh = mfma16(hh2[kb], bnh[kb], anh); anh = mfma16(hl2[kb], bnh[kb], anh);
        }
#pragma unroll
        for (int kb = 4; kb < 8; kb++) {
            ar = mfma16(hh2[kb - 4], br[kb], ar); ar = mfma16(hl2[kb - 4], br[kb], ar);
            az = mfma16(hh2[kb - 4], bz[kb], az); az = mfma16(hl2[kb - 4], bz[kb], az);
        }
        // elementwise (all reads of h before barrier; writes after)
        float hnv[4];
        int grv[4], bytv[4];
#pragma unroll
        for (int r = 0; r < 4; r++) {
            int row = (l >> 4) * 4 + r;
            int gr = sub * 16 + row;
            int byt = (colw * 2) ^ ((gr & 7) << 4);
            grv[r] = gr; bytv[r] = byt;
            float hold = bf2f(*(unsigned short*)(lds + OFF_HHI + gr * 256 + byt))
                       + bf2f(*(unsigned short*)(lds + OFF_HLO + gr * 256 + byt));
            float hn = hold;
            if (degp[row] > 0) {
                float rg = sigmoidf_(ar[r] + bir);
                float zg = sigmoidf_(az[r] + biz);
                float ng = tanhf(ani[r] + bin + rg * (anh[r] + bhn));
                hn = (1.f - zg) * ng + zg * hold;
            }
            hnv[r] = hn;
        }
        __syncthreads();   // all h/mg reads complete before overwrite
#pragma unroll
        for (int r = 0; r < 4; r++) {
            float hn = hnv[r];
            unsigned short h16 = f2bf(hn);
            *(unsigned short*)(lds + OFF_HHI + grv[r] * 256 + bytv[r]) = h16;
            *(unsigned short*)(lds + OFF_HLO + grv[r] * 256 + bytv[r]) = f2bf(hn - bf2f(h16));
            hout[(size_t)(b * 64 + grv[r]) * 128 + colw] = hn;
        }
    }

    // ===== readout (last pass): B direct from global =====
    if (last) {
        __syncthreads();
        const int lr = l & 15;
        const int grow = sub * 16 + lr;
        short8 rh[4], rl[4], xh[4], xl[4];
#pragma unroll
        for (int kb = 0; kb < 4; kb++) {
            int sw2 = kb * 64 + ((l >> 4) * 16);
            rh[kb] = *(const short8*)(lds + OFF_HHI + grow * 256 + (sw2 ^ ((grow & 7) << 4)));
            rl[kb] = *(const short8*)(lds + OFF_HLO + grow * 256 + (sw2 ^ ((grow & 7) << 4)));
            const float* p = nodes + (size_t)(b * 64 + grow) * 128 + kb * 32 + (l >> 4) * 8;
            short8 vh, vl;
#pragma unroll
            for (int j = 0; j < 8; j++) {
                float v = p[j];
                unsigned short hv = f2bf(v);
                vh[j] = (short)hv;
                vl[j] = (short)f2bf(v - bf2f(hv));
            }
            xh[kb] = vh; xl[kb] = vl;
        }
        short8 be4[4], bg8[8];
#pragma unroll
        for (int kb = 0; kb < 4; kb++)
            be4[kb] = *(const short8*)&pk[(size_t)(256 + w * 4 + kb) * 512 + l * 8];
#pragma unroll
        for (int kb = 0; kb < 8; kb++)
            bg8[kb] = *(const short8*)&pk[(size_t)(288 + w * 8 + kb) * 512 + l * 8];
        f32x4 ae = {0,0,0,0}, ag = {0,0,0,0};
#pragma unroll
        for (int kb = 0; kb < 4; kb++) {
            ae = mfma16(rh[kb], be4[kb], ae);     ae = mfma16(rl[kb], be4[kb], ae);
            ag = mfma16(rh[kb], bg8[kb], ag);     ag = mfma16(rl[kb], bg8[kb], ag);
            ag = mfma16(xh[kb], bg8[4 + kb], ag); ag = mfma16(xl[kb], bg8[4 + kb], ag);
        }
        float bev = b_emb[colw], bgv = b_gate[colw];
        float s = 0.f;
#pragma unroll
        for (int r = 0; r < 4; r++)
            if (degp[(l >> 4) * 4 + r] > 0)
                s += sigmoidf_(ag[r] + bgv) * (ae[r] + bev);
        s += __shfl_xor(s, 16);
        s += __shfl_xor(s, 32);
        if (l < 16) part[(size_t)blockIdx.x * 128 + w * 16 + l] = s;
    }
}

__global__ __launch_bounds__(256) void reduce_out(
    const float* __restrict__ part, float* __restrict__ out)
{
    int idx = blockIdx.x * 256 + threadIdx.x;   // 8192
    int b = idx >> 7, c = idx & 127;
    out[idx] = part[(size_t)(b * 4 + 0) * 128 + c] + part[(size_t)(b * 4 + 1) * 128 + c]
             + part[(size_t)(b * 4 + 2) * 128 + c] + part[(size_t)(b * 4 + 3) * 128 + c];
}

extern "C" void kernel_launch(void* const* d_in, const int* in_sizes, int n_in,
                              void* d_out, int out_size, void* d_ws, size_t ws_size,
                              hipStream_t stream) {
    const float* nodes  = (const float*)d_in[0];
    const float* edges  = (const float*)d_in[1];
    const float* W_att  = (const float*)d_in[2];
    const float* W_msg  = (const float*)d_in[4];
    const float* b_msg  = (const float*)d_in[5];
    const float* W_i    = (const float*)d_in[6];
    const float* b_i    = (const float*)d_in[7];
    const float* W_h    = (const float*)d_in[8];
    const float* b_h    = (const float*)d_in[9];
    const float* W_gate = (const float*)d_in[10];
    const float* b_gate = (const float*)d_in[11];
    const float* W_emb  = (const float*)d_in[12];
    const float* b_emb  = (const float*)d_in[13];
    float* out = (float*)d_out;

    char* ws = (char*)d_ws;
    unsigned short* pk    = (unsigned short*)ws; ws += (size_t)PK_TILES * 512 * 2;  // 352 KB
    unsigned short* nbr_g = (unsigned short*)ws; ws += (size_t)4096 * 64 * 2;       // 512 KB
    int*   deg_g = (int*)ws;   ws += 4096 * 4;                                      // 16 KB
    float* hid0  = (float*)ws; ws += (size_t)4096 * 128 * 4;                        // 2 MB
    float* hid1  = (float*)ws; ws += (size_t)4096 * 128 * 4;                        // 2 MB
    float* part  = (float*)ws; ws += (size_t)256 * 128 * 4;                         // 128 KB

    fused_prep<<<108, 512, 0, stream>>>(W_att, W_msg, W_i, W_h, W_gate, W_emb,
                                        edges, pk, nbr_g, deg_g);
    pass_kernel<<<256, 512, 0, stream>>>(nodes, hid0, nodes, W_att, W_msg, b_msg,
                                         b_i, b_h, b_gate, b_emb, pk, nbr_g, deg_g, part, 0);
    pass_kernel<<<256, 512, 0, stream>>>(hid0, hid1, nodes, W_att, W_msg, b_msg,
                                         b_i, b_h, b_gate, b_emb, pk, nbr_g, deg_g, part, 0);
    pass_kernel<<<256, 512, 0, stream>>>(hid1, hid0, nodes, W_att, W_msg, b_msg,
                                         b_i, b_h, b_gate, b_emb, pk, nbr_g, deg_g, part, 1);
    reduce_out<<<32, 256, 0, stream>>>(part, out);
}